// Round 14
// baseline (204.596 us; speedup 1.0000x reference)
//
#include <hip/hip_runtime.h>
#include <hip/hip_fp16.h>

// out[n,c] = sum_{e: dst[e]==n} ( sum_k x[src[e],k]*W3[k]*x[dst[e],k] ) * x[src[e],c] * W2[c]
// B=1, N=100000, E=1600000, C=128.
//
// Pipeline (2 launches):
//   k_preproc   : ONE launch fusing hist -> scan -> place with device-scope
//                 counter barriers; fp16 pack runs continuously via a global
//                 atomic tile dispenser on all idle/finished blocks.
//                 Deadlock-safe: pack-only blocks never wait; role waits
//                 depend only on counts every block reaches unconditionally;
//                 launch_bounds(256,4) + 18.4KB LDS => all 512 blocks
//                 co-resident with 2x margin.
//   k_sort_accum: per-bin LDS counting sort + fused accumulation (R13-proven:
//                 fdot2 dot, hfma2 accum, dst prefetch, 4-deep ladder).
// Fallback: R1-style pure-atomic kernel if constraints unmet.

#define CCH 128
#define BSHIFT 5
#define BWIDTH 32              // nodes per bin
#define MAXBIN 4096            // supports N <= 131072 (17-bit src pack)
#define CH 8192                // edges per partition block
#define LDSCAP 1280            // max edges staged per bin (mean ~512)
#define TBINS 16               // bins per scan-role block
#define NBLKCAP 256            // max partition blocks supported by scan tile
#define NBA 512                // k_preproc grid

typedef _Float16 half2_t __attribute__((ext_vector_type(2)));

__device__ __forceinline__ float dot8_f16(const __half2* q, const half2_t* v) {
#if __has_builtin(__builtin_amdgcn_fdot2)
    const half2_t* qv = reinterpret_cast<const half2_t*>(q);
    float p = __builtin_amdgcn_fdot2(qv[0], v[0], 0.f, false);
    p = __builtin_amdgcn_fdot2(qv[1], v[1], p, false);
    p = __builtin_amdgcn_fdot2(qv[2], v[2], p, false);
    p = __builtin_amdgcn_fdot2(qv[3], v[3], p, false);
    return p;
#else
    const __half2* vv = reinterpret_cast<const __half2*>(v);
    __half2 t = __hmul2(q[0], vv[0]);
    t = __hfma2(q[1], vv[1], t);
    t = __hfma2(q[2], vv[2], t);
    t = __hfma2(q[3], vv[3], t);
    float2 tf = __half22float2(t);
    return tf.x + tf.y;
#endif
}

__device__ __forceinline__ void pack_body(const float* __restrict__ x,
                                          __half* __restrict__ xh,
                                          int n4, int i) {
    if (i < n4) {
        float4 v = reinterpret_cast<const float4*>(x)[i];
        __half2* o = reinterpret_cast<__half2*>(xh) + (size_t)i * 2;
        o[0] = __floats2half2_rn(v.x, v.y);
        o[1] = __floats2half2_rn(v.z, v.w);
    }
}

// ---------------- fused preprocessing: hist -> scan -> place, pack always ----------------

__global__ __launch_bounds__(256, 4) void k_preproc(
    const float* __restrict__ x, __half* __restrict__ xh, int n4,
    const int* __restrict__ src, const int* __restrict__ dst, int E,
    int NBIN, int NBLK, int nb1,
    int* __restrict__ hist_bm, int* __restrict__ partial, int* __restrict__ blocksum,
    unsigned int* __restrict__ coarse,
    unsigned int* __restrict__ bar, unsigned int* __restrict__ packCur)
{
    __shared__ int smem[4608];                // union: hist 4096 | scan 4368 | place 4608
    __shared__ unsigned st;
    const int bid = blockIdx.x;
    const int tid = threadIdx.x;
    const unsigned NBu = gridDim.x;
    const int T = (n4 + 255) >> 8;            // pack tiles of 256 float4s

    if (bid < NBLK) {
        // ---- P0: histogram of chunk bid ----
        int* cnt = smem;
        for (int b = tid; b < NBIN; b += 256) cnt[b] = 0;
        __syncthreads();
        {
            const int e0 = bid * CH;
            #pragma unroll
            for (int k = 0; k < CH / 1024; ++k) {
                const int g = (e0 >> 2) + k * 256 + tid;
                const int e = g << 2;
                if (e >= E) continue;
                if (e + 4 <= E) {
                    const int4 d4 = reinterpret_cast<const int4*>(dst)[g];
                    atomicAdd(&cnt[d4.x >> BSHIFT], 1);
                    atomicAdd(&cnt[d4.y >> BSHIFT], 1);
                    atomicAdd(&cnt[d4.z >> BSHIFT], 1);
                    atomicAdd(&cnt[d4.w >> BSHIFT], 1);
                } else {
                    for (int ee = e; ee < E; ++ee) atomicAdd(&cnt[dst[ee] >> BSHIFT], 1);
                }
            }
        }
        __syncthreads();
        {
            int* hb = hist_bm + (size_t)bid * NBIN;
            for (int b = tid; b < NBIN; b += 256) hb[b] = cnt[b];
        }
        // arrive bar0
        __syncthreads();
        if (tid == 0)
            __hip_atomic_fetch_add(&bar[0], 1u, __ATOMIC_RELEASE, __HIP_MEMORY_SCOPE_AGENT);

        if (bid < nb1) {
            // wait bar0 (hist_bm complete), then scan role
            if (tid == 0)
                while (__hip_atomic_load(&bar[0], __ATOMIC_ACQUIRE, __HIP_MEMORY_SCOPE_AGENT) < NBu)
                    __builtin_amdgcn_s_sleep(8);
            __syncthreads();

            int (*tile)[NBLKCAP + 1] = reinterpret_cast<int(*)[NBLKCAP + 1]>(smem);
            int* sdt = smem + TBINS * (NBLKCAP + 1);
            const int B0 = bid * TBINS;
            for (int g = tid; g < TBINS * (NBLKCAP + 1); g += 256)
                (&tile[0][0])[g] = 0;
            __syncthreads();
            for (int g = tid; g < NBLK * TBINS; g += 256) {
                const int blk = g >> 4;
                const int tb  = g & (TBINS - 1);
                const int bin = B0 + tb;
                if (bin < NBIN) tile[tb][blk] = hist_bm[(size_t)blk * NBIN + bin];
            }
            __syncthreads();
            const int tb  = tid >> 4;
            const int bk0 = (tid & 15) * 16;
            int v[16];
            int local = 0;
            #pragma unroll
            for (int k = 0; k < 16; ++k) { v[k] = tile[tb][bk0 + k]; local += v[k]; }
            sdt[tid] = local;
            __syncthreads();
            #pragma unroll
            for (int off = 1; off < 256; off <<= 1) {
                int val = (tid >= off) ? sdt[tid - off] : 0;
                __syncthreads();
                sdt[tid] += val;
                __syncthreads();
            }
            const int incl = sdt[tid];
            int run = incl - local;
            if (tid == 255) blocksum[bid] = incl;   // raw total
            const int bin = B0 + tb;
            if (bin < NBIN) {
                #pragma unroll
                for (int k = 0; k < 16; ++k) {
                    const int blk = bk0 + k;
                    if (blk < NBLK) partial[(size_t)bin * NBLK + blk] = run;
                    run += v[k];
                }
            }
        }
        // arrive bar1
        __syncthreads();
        if (tid == 0)
            __hip_atomic_fetch_add(&bar[1], 1u, __ATOMIC_RELEASE, __HIP_MEMORY_SCOPE_AGENT);
        // wait bar1 (partial/blocksum complete), then place role
        if (tid == 0)
            while (__hip_atomic_load(&bar[1], __ATOMIC_ACQUIRE, __HIP_MEMORY_SCOPE_AGENT) < NBu)
                __builtin_amdgcn_s_sleep(8);
        __syncthreads();

        {   // in-LDS exclusive scan of raw blocksum totals
            int* lcur = smem;                        // 4096
            int* sd   = smem + MAXBIN;               // 256
            int* sb   = smem + MAXBIN + 256;         // 256
            sd[tid] = (tid < nb1) ? blocksum[tid] : 0;
            const int own = sd[tid];
            __syncthreads();
            #pragma unroll
            for (int off = 1; off < 256; off <<= 1) {
                int val = (tid >= off) ? sd[tid - off] : 0;
                __syncthreads();
                sd[tid] += val;
                __syncthreads();
            }
            sb[tid] = sd[tid] - own;
            __syncthreads();

            for (int b = tid; b < NBIN; b += 256)
                lcur[b] = partial[(size_t)b * NBLK + bid] + sb[b / TBINS];
            __syncthreads();

            const int e0 = bid * CH;
            #pragma unroll
            for (int k = 0; k < CH / 1024; ++k) {
                const int g = (e0 >> 2) + k * 256 + tid;
                const int e = g << 2;
                if (e >= E) continue;
                if (e + 4 <= E) {
                    const int4 d4 = reinterpret_cast<const int4*>(dst)[g];
                    const int4 s4 = reinterpret_cast<const int4*>(src)[g];
                    int p;
                    p = atomicAdd(&lcur[d4.x >> BSHIFT], 1);
                    coarse[p] = (unsigned)s4.x | ((unsigned)(d4.x & (BWIDTH - 1)) << 17);
                    p = atomicAdd(&lcur[d4.y >> BSHIFT], 1);
                    coarse[p] = (unsigned)s4.y | ((unsigned)(d4.y & (BWIDTH - 1)) << 17);
                    p = atomicAdd(&lcur[d4.z >> BSHIFT], 1);
                    coarse[p] = (unsigned)s4.z | ((unsigned)(d4.z & (BWIDTH - 1)) << 17);
                    p = atomicAdd(&lcur[d4.w >> BSHIFT], 1);
                    coarse[p] = (unsigned)s4.w | ((unsigned)(d4.w & (BWIDTH - 1)) << 17);
                } else {
                    for (int ee = e; ee < E; ++ee) {
                        const int d = dst[ee], s = src[ee];
                        int p = atomicAdd(&lcur[d >> BSHIFT], 1);
                        coarse[p] = (unsigned)s | ((unsigned)(d & (BWIDTH - 1)) << 17);
                    }
                }
            }
        }
    } else {
        // pack-only block: arrive both barriers immediately (never waits)
        __syncthreads();
        if (tid == 0) {
            __hip_atomic_fetch_add(&bar[0], 1u, __ATOMIC_RELEASE, __HIP_MEMORY_SCOPE_AGENT);
            __hip_atomic_fetch_add(&bar[1], 1u, __ATOMIC_RELEASE, __HIP_MEMORY_SCOPE_AGENT);
        }
    }

    // ---- pack drain: all blocks pull 8-tile chunks from the global cursor ----
    for (;;) {
        __syncthreads();
        if (tid == 0) st = atomicAdd(packCur, 8u);
        __syncthreads();
        const unsigned t0 = st;
        if (t0 >= (unsigned)T) break;
        #pragma unroll
        for (int k = 0; k < 8; ++k) {
            const unsigned t = t0 + k;
            if (t < (unsigned)T) pack_body(x, xh, n4, (int)t * 256 + tid);
        }
    }
}

// ---------------- per-bin LDS counting sort + fused accumulation (R13) ----------------

__global__ __launch_bounds__(256) void k_sort_accum(
    const __half* __restrict__ xh,
    const float* __restrict__ W2,
    const float* __restrict__ W3,
    const unsigned int* __restrict__ coarse,
    const int* __restrict__ partial, const int* __restrict__ blocksum,
    int NBIN, int NBLK, int nb1, int E, int N,
    float* __restrict__ out)
{
    __shared__ unsigned int raw[LDSCAP];
    __shared__ int srcl[LDSCAP];
    __shared__ int cnt[BWIDTH], offs[BWIDTH], cur[BWIDTH];

    const int bin  = blockIdx.x;
    const int tid  = threadIdx.x;
    const int lane = tid & 63;
    const int grp  = lane >> 4;
    const int sl   = lane & 15;
    const int gid  = (tid >> 6) * 4 + grp;
    const int choff = sl << 4;
    const char* xb = (const char*)xh;

    union H { int4 i4; __half2 h[4]; };

    const int node0 = (bin << BSHIFT) + gid * 2;
    const int node1 = node0 + 1;
    H uD0, uD1;
    uD0.i4 = make_int4(0, 0, 0, 0);
    uD1.i4 = make_int4(0, 0, 0, 0);
    if (node0 < N) uD0.i4 = *reinterpret_cast<const int4*>(xb + (((size_t)node0) << 8) + choff);
    if (node1 < N) uD1.i4 = *reinterpret_cast<const int4*>(xb + (((size_t)node1) << 8) + choff);

    const int j1 = bin / TBINS;
    const int j2 = (bin + 1) / TBINS;
    int s = 0;
    #pragma unroll
    for (int k = 0; k < 4; ++k) {
        const int idx = lane + k * 64;
        if (idx < j1) s += blocksum[idx];
    }
    #pragma unroll
    for (int off = 32; off > 0; off >>= 1) s += __shfl_xor(s, off, 64);
    const int pref1 = s;
    const int pref2 = pref1 + ((j2 > j1 && j2 <= nb1) ? blocksum[j1] : 0);

    const size_t i0 = (size_t)bin * NBLK;
    const int beg = partial[i0] + pref1;
    const int end = (bin + 1 < NBIN) ? partial[i0 + NBLK] + pref2 : E;
    const int mtot = end - beg;
    const int m = (mtot < LDSCAP) ? mtot : LDSCAP;

    if (tid < BWIDTH) cnt[tid] = 0;
    __syncthreads();

    for (int i = tid; i < m; i += 256) {
        unsigned u = coarse[beg + i];
        raw[i] = u;
        atomicAdd(&cnt[u >> 17], 1);
    }
    __syncthreads();

    if (tid < BWIDTH) {
        int c = cnt[tid];
        int v = c;
        #pragma unroll
        for (int d2 = 1; d2 < BWIDTH; d2 <<= 1) {
            int t2 = __shfl_up(v, d2, 64);
            if (tid >= d2) v += t2;
        }
        offs[tid] = v - c;
        cur[tid]  = v - c;
    }
    __syncthreads();

    for (int i = tid; i < m; i += 256) {
        const unsigned u = raw[i];
        const int p = atomicAdd(&cur[u >> 17], 1);
        srcl[p] = (int)(u & 0x1FFFFu);
    }
    __syncthreads();

    const float4 w3a = *reinterpret_cast<const float4*>(W3 + sl * 8);
    const float4 w3b = *reinterpret_cast<const float4*>(W3 + sl * 8 + 4);
    const float4 w2a = *reinterpret_cast<const float4*>(W2 + sl * 8);
    const float4 w2b = *reinterpret_cast<const float4*>(W2 + sl * 8 + 4);

    #pragma unroll
    for (int i = 0; i < 2; ++i) {
        const int node = (i == 0) ? node0 : node1;
        if (node >= N) continue;
        const int dl = gid * 2 + i;
        const H uD = (i == 0) ? uD0 : uD1;

        const float2 e0 = __half22float2(uD.h[0]);
        const float2 e1 = __half22float2(uD.h[1]);
        const float2 e2 = __half22float2(uD.h[2]);
        const float2 e3 = __half22float2(uD.h[3]);
        half2_t vh[4];
        {
            __half2 t0 = __floats2half2_rn(w3a.x * e0.x, w3a.y * e0.y);
            __half2 t1 = __floats2half2_rn(w3a.z * e1.x, w3a.w * e1.y);
            __half2 t2 = __floats2half2_rn(w3b.x * e2.x, w3b.y * e2.y);
            __half2 t3 = __floats2half2_rn(w3b.z * e3.x, w3b.w * e3.y);
            vh[0] = *reinterpret_cast<half2_t*>(&t0);
            vh[1] = *reinterpret_cast<half2_t*>(&t1);
            vh[2] = *reinterpret_cast<half2_t*>(&t2);
            vh[3] = *reinterpret_cast<half2_t*>(&t3);
        }

        __half2 acc[4];
        acc[0] = __floats2half2_rn(0.f, 0.f);
        acc[1] = acc[0]; acc[2] = acc[0]; acc[3] = acc[0];

        const int b0 = offs[dl];
        const int c  = cnt[dl];

        int j = 0;
        for (; j + 4 <= c; j += 4) {
            const int s0 = srcl[b0 + j];
            const int s1 = srcl[b0 + j + 1];
            const int s2 = srcl[b0 + j + 2];
            const int s3 = srcl[b0 + j + 3];
            H u0, u1, u2, u3;
            u0.i4 = *reinterpret_cast<const int4*>(xb + (((size_t)s0) << 8) + choff);
            u1.i4 = *reinterpret_cast<const int4*>(xb + (((size_t)s1) << 8) + choff);
            u2.i4 = *reinterpret_cast<const int4*>(xb + (((size_t)s2) << 8) + choff);
            u3.i4 = *reinterpret_cast<const int4*>(xb + (((size_t)s3) << 8) + choff);
            float p0 = dot8_f16(u0.h, vh);
            float p1 = dot8_f16(u1.h, vh);
            float p2 = dot8_f16(u2.h, vh);
            float p3 = dot8_f16(u3.h, vh);
            #pragma unroll
            for (int off = 1; off < 16; off <<= 1) {
                p0 += __shfl_xor(p0, off, 64);
                p1 += __shfl_xor(p1, off, 64);
                p2 += __shfl_xor(p2, off, 64);
                p3 += __shfl_xor(p3, off, 64);
            }
            const __half2 ph0 = __half2half2(__float2half(p0));
            const __half2 ph1 = __half2half2(__float2half(p1));
            const __half2 ph2 = __half2half2(__float2half(p2));
            const __half2 ph3 = __half2half2(__float2half(p3));
            #pragma unroll
            for (int q = 0; q < 4; ++q) {
                acc[q] = __hfma2(ph0, u0.h[q], acc[q]);
                acc[q] = __hfma2(ph1, u1.h[q], acc[q]);
                acc[q] = __hfma2(ph2, u2.h[q], acc[q]);
                acc[q] = __hfma2(ph3, u3.h[q], acc[q]);
            }
        }
        for (; j < c; ++j) {
            H u0;
            u0.i4 = *reinterpret_cast<const int4*>(
                xb + (((size_t)srcl[b0 + j]) << 8) + choff);
            float p = dot8_f16(u0.h, vh);
            #pragma unroll
            for (int off = 1; off < 16; off <<= 1) p += __shfl_xor(p, off, 64);
            const __half2 ph = __half2half2(__float2half(p));
            #pragma unroll
            for (int q = 0; q < 4; ++q) acc[q] = __hfma2(ph, u0.h[q], acc[q]);
        }
        for (int i2 = LDSCAP; i2 < mtot; ++i2) {
            const unsigned u = coarse[beg + i2];
            if ((int)(u >> 17) != dl) continue;
            H u0;
            u0.i4 = *reinterpret_cast<const int4*>(
                xb + (((size_t)(u & 0x1FFFFu)) << 8) + choff);
            float p = dot8_f16(u0.h, vh);
            #pragma unroll
            for (int off = 1; off < 16; off <<= 1) p += __shfl_xor(p, off, 64);
            const __half2 ph = __half2half2(__float2half(p));
            #pragma unroll
            for (int q = 0; q < 4; ++q) acc[q] = __hfma2(ph, u0.h[q], acc[q]);
        }

        const float2 a0 = __half22float2(acc[0]);
        const float2 a1 = __half22float2(acc[1]);
        const float2 a2 = __half22float2(acc[2]);
        const float2 a3 = __half22float2(acc[3]);
        float4 oA = make_float4(a0.x * w2a.x, a0.y * w2a.y, a1.x * w2a.z, a1.y * w2a.w);
        float4 oB = make_float4(a2.x * w2b.x, a2.y * w2b.y, a3.x * w2b.z, a3.y * w2b.w);
        float* orow = out + (size_t)node * CCH + sl * 8;
        *reinterpret_cast<float4*>(orow)     = oA;
        *reinterpret_cast<float4*>(orow + 4) = oB;
    }
}

// ---------------- last-resort fallback: pure fp32 atomics (R1) ----------------

__global__ __launch_bounds__(256) void edge_gather_scatter(
    const float* __restrict__ x, const int* __restrict__ edge_index,
    const float* __restrict__ W2, const float* __restrict__ W3,
    float* __restrict__ out, int E)
{
    const int e    = (blockIdx.x * blockDim.x + threadIdx.x) >> 6;
    const int lane = threadIdx.x & 63;
    if (e >= E) return;
    const int s = edge_index[e];
    const int d = edge_index[E + e];
    const float2 xs = *reinterpret_cast<const float2*>(x + (size_t)s * CCH + lane * 2);
    const float2 xd = *reinterpret_cast<const float2*>(x + (size_t)d * CCH + lane * 2);
    const float2 w3 = *reinterpret_cast<const float2*>(W3 + lane * 2);
    const float2 w2 = *reinterpret_cast<const float2*>(W2 + lane * 2);
    float p = xs.x * w3.x * xd.x + xs.y * w3.y * xd.y;
    #pragma unroll
    for (int off = 32; off > 0; off >>= 1) p += __shfl_xor(p, off, 64);
    float* o = out + (size_t)d * CCH + lane * 2;
    atomicAdd(o,     p * xs.x * w2.x);
    atomicAdd(o + 1, p * xs.y * w2.y);
}

// ---------------- launch ----------------

extern "C" void kernel_launch(void* const* d_in, const int* in_sizes, int n_in,
                              void* d_out, int out_size, void* d_ws, size_t ws_size,
                              hipStream_t stream) {
    const float* x          = (const float*)d_in[0];
    const int*   edge_index = (const int*)  d_in[1];
    const float* W2         = (const float*)d_in[2];
    const float* W3         = (const float*)d_in[3];
    float*       out        = (float*)d_out;

    const int E = in_sizes[1] / 2;
    const int N = out_size / CCH;
    const int* src = edge_index;
    const int* dst = edge_index + E;

    const int NBIN = (N + BWIDTH - 1) >> BSHIFT;
    const int NBLK = (E + CH - 1) / CH;
    const long long Mll = (long long)NBIN * NBLK;
    const int M = (int)Mll;
    const int nb1 = (NBIN + TBINS - 1) / TBINS;

    const size_t xh_bytes = (size_t)N * CCH * 2;
    const size_t need = xh_bytes + (size_t)E * 4 + 2 * (size_t)M * 4 + 1024 * 4 + 64;

    const bool aligned16 = (((uintptr_t)src & 15) == 0) && (((uintptr_t)dst & 15) == 0);

    if (N <= (1 << 17) && NBIN <= MAXBIN && NBLK <= NBLKCAP && Mll <= (1LL << 20) &&
        nb1 <= 256 && NBLK < NBA && nb1 < NBA && aligned16 && ws_size >= need) {
        char* base = (char*)d_ws;
        __half* xh        = (__half*)base;       base += xh_bytes;
        unsigned* coarse  = (unsigned*)base;     base += (size_t)E * 4;
        int* hist_bm      = (int*)base;          base += (size_t)M * 4;
        int* partial      = (int*)base;          base += (size_t)M * 4;
        int* blocksum     = (int*)base;          base += 1024 * 4;
        unsigned* bar     = (unsigned*)base;     // bar[0..1], packCur at bar[2]
        unsigned* packCur = bar + 2;

        const int n4 = N * CCH / 4;

        hipMemsetAsync(bar, 0, 16, stream);
        k_preproc<<<NBA, 256, 0, stream>>>(x, xh, n4, src, dst, E,
                                           NBIN, NBLK, nb1,
                                           hist_bm, partial, blocksum, coarse,
                                           bar, packCur);
        k_sort_accum<<<NBIN, 256, 0, stream>>>(xh, W2, W3, coarse,
                                               partial, blocksum,
                                               NBIN, NBLK, nb1, E, N, out);
        return;
    }

    // last resort: pure atomics
    hipMemsetAsync(d_out, 0, (size_t)out_size * sizeof(float), stream);
    const int grid = (E * 64 + 255) / 256;
    edge_gather_scatter<<<grid, 256, 0, stream>>>(x, edge_index, W2, W3, out, E);
}

// Round 15
// 195.885 us; speedup vs baseline: 1.0445x; 1.0445x over previous
//
#include <hip/hip_runtime.h>
#include <hip/hip_fp16.h>

// out[n,c] = sum_{e: dst[e]==n} ( sum_k x[src[e],k]*W3[k]*x[dst[e],k] ) * x[src[e],c] * W2[c]
// B=1, N=100000, E=1600000, C=128.
//
// Pipeline (2 launches):
//   k_preproc   : ONE launch fusing hist -> scan -> place with device-scope
//                 counter barriers; fp16 pack runs continuously via a global
//                 atomic tile dispenser. R15 FIX: barrier waits poll with
//                 RELAXED loads (no per-poll L2 invalidate) and issue a single
//                 acquire fence after the count is reached. R14's ACQUIRE-in-
//                 loop caused an L2-invalidate storm (170us, VALUBusy 0.9%).
//   k_sort_accum: per-bin LDS counting sort + fused accumulation (R13-proven:
//                 fdot2 dot, hfma2 accum, dst prefetch, 4-deep ladder).
// Fallback: R1-style pure-atomic kernel if constraints unmet.

#define CCH 128
#define BSHIFT 5
#define BWIDTH 32              // nodes per bin
#define MAXBIN 4096            // supports N <= 131072 (17-bit src pack)
#define CH 8192                // edges per partition block
#define LDSCAP 1280            // max edges staged per bin (mean ~512)
#define TBINS 16               // bins per scan-role block
#define NBLKCAP 256            // max partition blocks supported by scan tile
#define NBA 512                // k_preproc grid

typedef _Float16 half2_t __attribute__((ext_vector_type(2)));

__device__ __forceinline__ float dot8_f16(const __half2* q, const half2_t* v) {
#if __has_builtin(__builtin_amdgcn_fdot2)
    const half2_t* qv = reinterpret_cast<const half2_t*>(q);
    float p = __builtin_amdgcn_fdot2(qv[0], v[0], 0.f, false);
    p = __builtin_amdgcn_fdot2(qv[1], v[1], p, false);
    p = __builtin_amdgcn_fdot2(qv[2], v[2], p, false);
    p = __builtin_amdgcn_fdot2(qv[3], v[3], p, false);
    return p;
#else
    const __half2* vv = reinterpret_cast<const __half2*>(v);
    __half2 t = __hmul2(q[0], vv[0]);
    t = __hfma2(q[1], vv[1], t);
    t = __hfma2(q[2], vv[2], t);
    t = __hfma2(q[3], vv[3], t);
    float2 tf = __half22float2(t);
    return tf.x + tf.y;
#endif
}

__device__ __forceinline__ void pack_body(const float* __restrict__ x,
                                          __half* __restrict__ xh,
                                          int n4, int i) {
    if (i < n4) {
        float4 v = reinterpret_cast<const float4*>(x)[i];
        __half2* o = reinterpret_cast<__half2*>(xh) + (size_t)i * 2;
        o[0] = __floats2half2_rn(v.x, v.y);
        o[1] = __floats2half2_rn(v.z, v.w);
    }
}

// RELAXED poll (no cache invalidate per iteration), then ONE acquire fence.
__device__ __forceinline__ void wait_count_relaxed(unsigned* p, unsigned target) {
    while (__hip_atomic_load(p, __ATOMIC_RELAXED, __HIP_MEMORY_SCOPE_AGENT) < target)
        __builtin_amdgcn_s_sleep(16);
    __builtin_amdgcn_fence(__ATOMIC_ACQUIRE, "agent");
}

// ---------------- fused preprocessing: hist -> scan -> place, pack always ----------------

__global__ __launch_bounds__(256, 4) void k_preproc(
    const float* __restrict__ x, __half* __restrict__ xh, int n4,
    const int* __restrict__ src, const int* __restrict__ dst, int E,
    int NBIN, int NBLK, int nb1,
    int* __restrict__ hist_bm, int* __restrict__ partial, int* __restrict__ blocksum,
    unsigned int* __restrict__ coarse,
    unsigned int* __restrict__ bar, unsigned int* __restrict__ packCur)
{
    __shared__ int smem[4608];                // union: hist 4096 | scan 4368 | place 4608
    __shared__ unsigned st;
    const int bid = blockIdx.x;
    const int tid = threadIdx.x;
    const unsigned NBu = gridDim.x;
    const int T = (n4 + 255) >> 8;            // pack tiles of 256 float4s

    if (bid < NBLK) {
        // ---- P0: histogram of chunk bid ----
        int* cnt = smem;
        for (int b = tid; b < NBIN; b += 256) cnt[b] = 0;
        __syncthreads();
        {
            const int e0 = bid * CH;
            #pragma unroll
            for (int k = 0; k < CH / 1024; ++k) {
                const int g = (e0 >> 2) + k * 256 + tid;
                const int e = g << 2;
                if (e >= E) continue;
                if (e + 4 <= E) {
                    const int4 d4 = reinterpret_cast<const int4*>(dst)[g];
                    atomicAdd(&cnt[d4.x >> BSHIFT], 1);
                    atomicAdd(&cnt[d4.y >> BSHIFT], 1);
                    atomicAdd(&cnt[d4.z >> BSHIFT], 1);
                    atomicAdd(&cnt[d4.w >> BSHIFT], 1);
                } else {
                    for (int ee = e; ee < E; ++ee) atomicAdd(&cnt[dst[ee] >> BSHIFT], 1);
                }
            }
        }
        __syncthreads();
        {
            int* hb = hist_bm + (size_t)bid * NBIN;
            for (int b = tid; b < NBIN; b += 256) hb[b] = cnt[b];
        }
        // arrive bar0 (release publishes hist_bm)
        __syncthreads();
        if (tid == 0)
            __hip_atomic_fetch_add(&bar[0], 1u, __ATOMIC_RELEASE, __HIP_MEMORY_SCOPE_AGENT);

        if (bid < nb1) {
            // wait bar0 (hist_bm complete), then scan role
            if (tid == 0) wait_count_relaxed(&bar[0], NBu);
            __syncthreads();

            int (*tile)[NBLKCAP + 1] = reinterpret_cast<int(*)[NBLKCAP + 1]>(smem);
            int* sdt = smem + TBINS * (NBLKCAP + 1);
            const int B0 = bid * TBINS;
            for (int g = tid; g < TBINS * (NBLKCAP + 1); g += 256)
                (&tile[0][0])[g] = 0;
            __syncthreads();
            for (int g = tid; g < NBLK * TBINS; g += 256) {
                const int blk = g >> 4;
                const int tb  = g & (TBINS - 1);
                const int bin = B0 + tb;
                if (bin < NBIN) tile[tb][blk] = hist_bm[(size_t)blk * NBIN + bin];
            }
            __syncthreads();
            const int tb  = tid >> 4;
            const int bk0 = (tid & 15) * 16;
            int v[16];
            int local = 0;
            #pragma unroll
            for (int k = 0; k < 16; ++k) { v[k] = tile[tb][bk0 + k]; local += v[k]; }
            sdt[tid] = local;
            __syncthreads();
            #pragma unroll
            for (int off = 1; off < 256; off <<= 1) {
                int val = (tid >= off) ? sdt[tid - off] : 0;
                __syncthreads();
                sdt[tid] += val;
                __syncthreads();
            }
            const int incl = sdt[tid];
            int run = incl - local;
            if (tid == 255) blocksum[bid] = incl;   // raw total
            const int bin = B0 + tb;
            if (bin < NBIN) {
                #pragma unroll
                for (int k = 0; k < 16; ++k) {
                    const int blk = bk0 + k;
                    if (blk < NBLK) partial[(size_t)bin * NBLK + blk] = run;
                    run += v[k];
                }
            }
        }
        // arrive bar1 (release publishes partial/blocksum)
        __syncthreads();
        if (tid == 0)
            __hip_atomic_fetch_add(&bar[1], 1u, __ATOMIC_RELEASE, __HIP_MEMORY_SCOPE_AGENT);
        // wait bar1, then place role
        if (tid == 0) wait_count_relaxed(&bar[1], NBu);
        __syncthreads();

        {   // in-LDS exclusive scan of raw blocksum totals
            int* lcur = smem;                        // 4096
            int* sd   = smem + MAXBIN;               // 256
            int* sb   = smem + MAXBIN + 256;         // 256
            sd[tid] = (tid < nb1) ? blocksum[tid] : 0;
            const int own = sd[tid];
            __syncthreads();
            #pragma unroll
            for (int off = 1; off < 256; off <<= 1) {
                int val = (tid >= off) ? sd[tid - off] : 0;
                __syncthreads();
                sd[tid] += val;
                __syncthreads();
            }
            sb[tid] = sd[tid] - own;
            __syncthreads();

            for (int b = tid; b < NBIN; b += 256)
                lcur[b] = partial[(size_t)b * NBLK + bid] + sb[b / TBINS];
            __syncthreads();

            const int e0 = bid * CH;
            #pragma unroll
            for (int k = 0; k < CH / 1024; ++k) {
                const int g = (e0 >> 2) + k * 256 + tid;
                const int e = g << 2;
                if (e >= E) continue;
                if (e + 4 <= E) {
                    const int4 d4 = reinterpret_cast<const int4*>(dst)[g];
                    const int4 s4 = reinterpret_cast<const int4*>(src)[g];
                    int p;
                    p = atomicAdd(&lcur[d4.x >> BSHIFT], 1);
                    coarse[p] = (unsigned)s4.x | ((unsigned)(d4.x & (BWIDTH - 1)) << 17);
                    p = atomicAdd(&lcur[d4.y >> BSHIFT], 1);
                    coarse[p] = (unsigned)s4.y | ((unsigned)(d4.y & (BWIDTH - 1)) << 17);
                    p = atomicAdd(&lcur[d4.z >> BSHIFT], 1);
                    coarse[p] = (unsigned)s4.z | ((unsigned)(d4.z & (BWIDTH - 1)) << 17);
                    p = atomicAdd(&lcur[d4.w >> BSHIFT], 1);
                    coarse[p] = (unsigned)s4.w | ((unsigned)(d4.w & (BWIDTH - 1)) << 17);
                } else {
                    for (int ee = e; ee < E; ++ee) {
                        const int d = dst[ee], s = src[ee];
                        int p = atomicAdd(&lcur[d >> BSHIFT], 1);
                        coarse[p] = (unsigned)s | ((unsigned)(d & (BWIDTH - 1)) << 17);
                    }
                }
            }
        }
    } else {
        // pack-only block: arrive both barriers immediately (never waits)
        __syncthreads();
        if (tid == 0) {
            __hip_atomic_fetch_add(&bar[0], 1u, __ATOMIC_RELEASE, __HIP_MEMORY_SCOPE_AGENT);
            __hip_atomic_fetch_add(&bar[1], 1u, __ATOMIC_RELEASE, __HIP_MEMORY_SCOPE_AGENT);
        }
    }

    // ---- pack drain: all blocks pull 8-tile chunks from the global cursor ----
    for (;;) {
        __syncthreads();
        if (tid == 0) st = atomicAdd(packCur, 8u);
        __syncthreads();
        const unsigned t0 = st;
        if (t0 >= (unsigned)T) break;
        #pragma unroll
        for (int k = 0; k < 8; ++k) {
            const unsigned t = t0 + k;
            if (t < (unsigned)T) pack_body(x, xh, n4, (int)t * 256 + tid);
        }
    }
}

// ---------------- per-bin LDS counting sort + fused accumulation (R13) ----------------

__global__ __launch_bounds__(256) void k_sort_accum(
    const __half* __restrict__ xh,
    const float* __restrict__ W2,
    const float* __restrict__ W3,
    const unsigned int* __restrict__ coarse,
    const int* __restrict__ partial, const int* __restrict__ blocksum,
    int NBIN, int NBLK, int nb1, int E, int N,
    float* __restrict__ out)
{
    __shared__ unsigned int raw[LDSCAP];
    __shared__ int srcl[LDSCAP];
    __shared__ int cnt[BWIDTH], offs[BWIDTH], cur[BWIDTH];

    const int bin  = blockIdx.x;
    const int tid  = threadIdx.x;
    const int lane = tid & 63;
    const int grp  = lane >> 4;
    const int sl   = lane & 15;
    const int gid  = (tid >> 6) * 4 + grp;
    const int choff = sl << 4;
    const char* xb = (const char*)xh;

    union H { int4 i4; __half2 h[4]; };

    const int node0 = (bin << BSHIFT) + gid * 2;
    const int node1 = node0 + 1;
    H uD0, uD1;
    uD0.i4 = make_int4(0, 0, 0, 0);
    uD1.i4 = make_int4(0, 0, 0, 0);
    if (node0 < N) uD0.i4 = *reinterpret_cast<const int4*>(xb + (((size_t)node0) << 8) + choff);
    if (node1 < N) uD1.i4 = *reinterpret_cast<const int4*>(xb + (((size_t)node1) << 8) + choff);

    const int j1 = bin / TBINS;
    const int j2 = (bin + 1) / TBINS;
    int s = 0;
    #pragma unroll
    for (int k = 0; k < 4; ++k) {
        const int idx = lane + k * 64;
        if (idx < j1) s += blocksum[idx];
    }
    #pragma unroll
    for (int off = 32; off > 0; off >>= 1) s += __shfl_xor(s, off, 64);
    const int pref1 = s;
    const int pref2 = pref1 + ((j2 > j1 && j2 <= nb1) ? blocksum[j1] : 0);

    const size_t i0 = (size_t)bin * NBLK;
    const int beg = partial[i0] + pref1;
    const int end = (bin + 1 < NBIN) ? partial[i0 + NBLK] + pref2 : E;
    const int mtot = end - beg;
    const int m = (mtot < LDSCAP) ? mtot : LDSCAP;

    if (tid < BWIDTH) cnt[tid] = 0;
    __syncthreads();

    for (int i = tid; i < m; i += 256) {
        unsigned u = coarse[beg + i];
        raw[i] = u;
        atomicAdd(&cnt[u >> 17], 1);
    }
    __syncthreads();

    if (tid < BWIDTH) {
        int c = cnt[tid];
        int v = c;
        #pragma unroll
        for (int d2 = 1; d2 < BWIDTH; d2 <<= 1) {
            int t2 = __shfl_up(v, d2, 64);
            if (tid >= d2) v += t2;
        }
        offs[tid] = v - c;
        cur[tid]  = v - c;
    }
    __syncthreads();

    for (int i = tid; i < m; i += 256) {
        const unsigned u = raw[i];
        const int p = atomicAdd(&cur[u >> 17], 1);
        srcl[p] = (int)(u & 0x1FFFFu);
    }
    __syncthreads();

    const float4 w3a = *reinterpret_cast<const float4*>(W3 + sl * 8);
    const float4 w3b = *reinterpret_cast<const float4*>(W3 + sl * 8 + 4);
    const float4 w2a = *reinterpret_cast<const float4*>(W2 + sl * 8);
    const float4 w2b = *reinterpret_cast<const float4*>(W2 + sl * 8 + 4);

    #pragma unroll
    for (int i = 0; i < 2; ++i) {
        const int node = (i == 0) ? node0 : node1;
        if (node >= N) continue;
        const int dl = gid * 2 + i;
        const H uD = (i == 0) ? uD0 : uD1;

        const float2 e0 = __half22float2(uD.h[0]);
        const float2 e1 = __half22float2(uD.h[1]);
        const float2 e2 = __half22float2(uD.h[2]);
        const float2 e3 = __half22float2(uD.h[3]);
        half2_t vh[4];
        {
            __half2 t0 = __floats2half2_rn(w3a.x * e0.x, w3a.y * e0.y);
            __half2 t1 = __floats2half2_rn(w3a.z * e1.x, w3a.w * e1.y);
            __half2 t2 = __floats2half2_rn(w3b.x * e2.x, w3b.y * e2.y);
            __half2 t3 = __floats2half2_rn(w3b.z * e3.x, w3b.w * e3.y);
            vh[0] = *reinterpret_cast<half2_t*>(&t0);
            vh[1] = *reinterpret_cast<half2_t*>(&t1);
            vh[2] = *reinterpret_cast<half2_t*>(&t2);
            vh[3] = *reinterpret_cast<half2_t*>(&t3);
        }

        __half2 acc[4];
        acc[0] = __floats2half2_rn(0.f, 0.f);
        acc[1] = acc[0]; acc[2] = acc[0]; acc[3] = acc[0];

        const int b0 = offs[dl];
        const int c  = cnt[dl];

        int j = 0;
        for (; j + 4 <= c; j += 4) {
            const int s0 = srcl[b0 + j];
            const int s1 = srcl[b0 + j + 1];
            const int s2 = srcl[b0 + j + 2];
            const int s3 = srcl[b0 + j + 3];
            H u0, u1, u2, u3;
            u0.i4 = *reinterpret_cast<const int4*>(xb + (((size_t)s0) << 8) + choff);
            u1.i4 = *reinterpret_cast<const int4*>(xb + (((size_t)s1) << 8) + choff);
            u2.i4 = *reinterpret_cast<const int4*>(xb + (((size_t)s2) << 8) + choff);
            u3.i4 = *reinterpret_cast<const int4*>(xb + (((size_t)s3) << 8) + choff);
            float p0 = dot8_f16(u0.h, vh);
            float p1 = dot8_f16(u1.h, vh);
            float p2 = dot8_f16(u2.h, vh);
            float p3 = dot8_f16(u3.h, vh);
            #pragma unroll
            for (int off = 1; off < 16; off <<= 1) {
                p0 += __shfl_xor(p0, off, 64);
                p1 += __shfl_xor(p1, off, 64);
                p2 += __shfl_xor(p2, off, 64);
                p3 += __shfl_xor(p3, off, 64);
            }
            const __half2 ph0 = __half2half2(__float2half(p0));
            const __half2 ph1 = __half2half2(__float2half(p1));
            const __half2 ph2 = __half2half2(__float2half(p2));
            const __half2 ph3 = __half2half2(__float2half(p3));
            #pragma unroll
            for (int q = 0; q < 4; ++q) {
                acc[q] = __hfma2(ph0, u0.h[q], acc[q]);
                acc[q] = __hfma2(ph1, u1.h[q], acc[q]);
                acc[q] = __hfma2(ph2, u2.h[q], acc[q]);
                acc[q] = __hfma2(ph3, u3.h[q], acc[q]);
            }
        }
        for (; j < c; ++j) {
            H u0;
            u0.i4 = *reinterpret_cast<const int4*>(
                xb + (((size_t)srcl[b0 + j]) << 8) + choff);
            float p = dot8_f16(u0.h, vh);
            #pragma unroll
            for (int off = 1; off < 16; off <<= 1) p += __shfl_xor(p, off, 64);
            const __half2 ph = __half2half2(__float2half(p));
            #pragma unroll
            for (int q = 0; q < 4; ++q) acc[q] = __hfma2(ph, u0.h[q], acc[q]);
        }
        for (int i2 = LDSCAP; i2 < mtot; ++i2) {
            const unsigned u = coarse[beg + i2];
            if ((int)(u >> 17) != dl) continue;
            H u0;
            u0.i4 = *reinterpret_cast<const int4*>(
                xb + (((size_t)(u & 0x1FFFFu)) << 8) + choff);
            float p = dot8_f16(u0.h, vh);
            #pragma unroll
            for (int off = 1; off < 16; off <<= 1) p += __shfl_xor(p, off, 64);
            const __half2 ph = __half2half2(__float2half(p));
            #pragma unroll
            for (int q = 0; q < 4; ++q) acc[q] = __hfma2(ph, u0.h[q], acc[q]);
        }

        const float2 a0 = __half22float2(acc[0]);
        const float2 a1 = __half22float2(acc[1]);
        const float2 a2 = __half22float2(acc[2]);
        const float2 a3 = __half22float2(acc[3]);
        float4 oA = make_float4(a0.x * w2a.x, a0.y * w2a.y, a1.x * w2a.z, a1.y * w2a.w);
        float4 oB = make_float4(a2.x * w2b.x, a2.y * w2b.y, a3.x * w2b.z, a3.y * w2b.w);
        float* orow = out + (size_t)node * CCH + sl * 8;
        *reinterpret_cast<float4*>(orow)     = oA;
        *reinterpret_cast<float4*>(orow + 4) = oB;
    }
}

// ---------------- last-resort fallback: pure fp32 atomics (R1) ----------------

__global__ __launch_bounds__(256) void edge_gather_scatter(
    const float* __restrict__ x, const int* __restrict__ edge_index,
    const float* __restrict__ W2, const float* __restrict__ W3,
    float* __restrict__ out, int E)
{
    const int e    = (blockIdx.x * blockDim.x + threadIdx.x) >> 6;
    const int lane = threadIdx.x & 63;
    if (e >= E) return;
    const int s = edge_index[e];
    const int d = edge_index[E + e];
    const float2 xs = *reinterpret_cast<const float2*>(x + (size_t)s * CCH + lane * 2);
    const float2 xd = *reinterpret_cast<const float2*>(x + (size_t)d * CCH + lane * 2);
    const float2 w3 = *reinterpret_cast<const float2*>(W3 + lane * 2);
    const float2 w2 = *reinterpret_cast<const float2*>(W2 + lane * 2);
    float p = xs.x * w3.x * xd.x + xs.y * w3.y * xd.y;
    #pragma unroll
    for (int off = 32; off > 0; off >>= 1) p += __shfl_xor(p, off, 64);
    float* o = out + (size_t)d * CCH + lane * 2;
    atomicAdd(o,     p * xs.x * w2.x);
    atomicAdd(o + 1, p * xs.y * w2.y);
}

// ---------------- launch ----------------

extern "C" void kernel_launch(void* const* d_in, const int* in_sizes, int n_in,
                              void* d_out, int out_size, void* d_ws, size_t ws_size,
                              hipStream_t stream) {
    const float* x          = (const float*)d_in[0];
    const int*   edge_index = (const int*)  d_in[1];
    const float* W2         = (const float*)d_in[2];
    const float* W3         = (const float*)d_in[3];
    float*       out        = (float*)d_out;

    const int E = in_sizes[1] / 2;
    const int N = out_size / CCH;
    const int* src = edge_index;
    const int* dst = edge_index + E;

    const int NBIN = (N + BWIDTH - 1) >> BSHIFT;
    const int NBLK = (E + CH - 1) / CH;
    const long long Mll = (long long)NBIN * NBLK;
    const int M = (int)Mll;
    const int nb1 = (NBIN + TBINS - 1) / TBINS;

    const size_t xh_bytes = (size_t)N * CCH * 2;
    const size_t need = xh_bytes + (size_t)E * 4 + 2 * (size_t)M * 4 + 1024 * 4 + 64;

    const bool aligned16 = (((uintptr_t)src & 15) == 0) && (((uintptr_t)dst & 15) == 0);

    if (N <= (1 << 17) && NBIN <= MAXBIN && NBLK <= NBLKCAP && Mll <= (1LL << 20) &&
        nb1 <= 256 && NBLK < NBA && nb1 < NBA && aligned16 && ws_size >= need) {
        char* base = (char*)d_ws;
        __half* xh        = (__half*)base;       base += xh_bytes;
        unsigned* coarse  = (unsigned*)base;     base += (size_t)E * 4;
        int* hist_bm      = (int*)base;          base += (size_t)M * 4;
        int* partial      = (int*)base;          base += (size_t)M * 4;
        int* blocksum     = (int*)base;          base += 1024 * 4;
        unsigned* bar     = (unsigned*)base;     // bar[0..1], packCur at bar[2]
        unsigned* packCur = bar + 2;

        const int n4 = N * CCH / 4;

        hipMemsetAsync(bar, 0, 16, stream);
        k_preproc<<<NBA, 256, 0, stream>>>(x, xh, n4, src, dst, E,
                                           NBIN, NBLK, nb1,
                                           hist_bm, partial, blocksum, coarse,
                                           bar, packCur);
        k_sort_accum<<<NBIN, 256, 0, stream>>>(xh, W2, W3, coarse,
                                               partial, blocksum,
                                               NBIN, NBLK, nb1, E, N, out);
        return;
    }

    // last resort: pure atomics
    hipMemsetAsync(d_out, 0, (size_t)out_size * sizeof(float), stream);
    const int grid = (E * 64 + 255) / 256;
    edge_gather_scatter<<<grid, 256, 0, stream>>>(x, edge_index, W2, W3, out, E);
}

// Round 16
// 154.699 us; speedup vs baseline: 1.3225x; 1.2662x over previous
//
#include <hip/hip_runtime.h>
#include <hip/hip_fp16.h>

// out[n,c] = sum_{e: dst[e]==n} ( sum_k x[src[e],k]*W3[k]*x[dst[e],k] ) * x[src[e],c] * W2[c]
// B=1, N=100000, E=1600000, C=128.
//
// Pipeline (2 launches):
//   k_preproc   : ONE launch fusing hist -> scan -> place. R16: NO dynamic
//                 work dispenser (R14/R15's atomicAdd cursor = 1563 dependent
//                 same-address RMW round trips ~ 160us). fp16 pack now runs on
//                 static per-block ranges on the 316 non-role blocks; barriers
//                 are participant-only counters (196 one-shot release-adds),
//                 128B apart. Waits: RELAXED poll + one acquire fence (R15-
//                 proven correct).
//   k_sort_accum: per-bin LDS counting sort + fused accumulation (R13-proven:
//                 fdot2 dot, hfma2 accum, dst prefetch, 4-deep ladder; 72us).
// Fallback: R1-style pure-atomic kernel if constraints unmet.

#define CCH 128
#define BSHIFT 5
#define BWIDTH 32              // nodes per bin
#define MAXBIN 4096            // supports N <= 131072 (17-bit src pack)
#define CH 8192                // edges per partition block
#define LDSCAP 1280            // max edges staged per bin (mean ~512)
#define TBINS 16               // bins per scan-role block
#define NBLKCAP 256            // max partition blocks supported by scan tile
#define NBA 512                // k_preproc grid

typedef _Float16 half2_t __attribute__((ext_vector_type(2)));

__device__ __forceinline__ float dot8_f16(const __half2* q, const half2_t* v) {
#if __has_builtin(__builtin_amdgcn_fdot2)
    const half2_t* qv = reinterpret_cast<const half2_t*>(q);
    float p = __builtin_amdgcn_fdot2(qv[0], v[0], 0.f, false);
    p = __builtin_amdgcn_fdot2(qv[1], v[1], p, false);
    p = __builtin_amdgcn_fdot2(qv[2], v[2], p, false);
    p = __builtin_amdgcn_fdot2(qv[3], v[3], p, false);
    return p;
#else
    const __half2* vv = reinterpret_cast<const __half2*>(v);
    __half2 t = __hmul2(q[0], vv[0]);
    t = __hfma2(q[1], vv[1], t);
    t = __hfma2(q[2], vv[2], t);
    t = __hfma2(q[3], vv[3], t);
    float2 tf = __half22float2(t);
    return tf.x + tf.y;
#endif
}

__device__ __forceinline__ void pack_body(const float* __restrict__ x,
                                          __half* __restrict__ xh,
                                          int n4, int i) {
    if (i < n4) {
        float4 v = reinterpret_cast<const float4*>(x)[i];
        __half2* o = reinterpret_cast<__half2*>(xh) + (size_t)i * 2;
        o[0] = __floats2half2_rn(v.x, v.y);
        o[1] = __floats2half2_rn(v.z, v.w);
    }
}

// RELAXED poll (no cache invalidate per iteration), then ONE acquire fence.
__device__ __forceinline__ void wait_count_relaxed(unsigned* p, unsigned target) {
    while (__hip_atomic_load(p, __ATOMIC_RELAXED, __HIP_MEMORY_SCOPE_AGENT) < target)
        __builtin_amdgcn_s_sleep(8);
    __builtin_amdgcn_fence(__ATOMIC_ACQUIRE, "agent");
}

// ---------------- fused preprocessing: hist -> scan -> place | static pack ----------------
// bar[0]  (byte 0)   : hist arrivals, target NBLK
// bar[32] (byte 128) : scan arrivals, target nb1

__global__ __launch_bounds__(256, 4) void k_preproc(
    const float* __restrict__ x, __half* __restrict__ xh, int n4,
    const int* __restrict__ src, const int* __restrict__ dst, int E,
    int NBIN, int NBLK, int nb1,
    int* __restrict__ hist_bm, int* __restrict__ partial, int* __restrict__ blocksum,
    unsigned int* __restrict__ coarse,
    unsigned int* __restrict__ bar)
{
    __shared__ int smem[4608];                // union: hist 4096 | scan 4368 | place 4608
    const int bid = blockIdx.x;
    const int tid = threadIdx.x;
    const int T = (n4 + 255) >> 8;            // pack tiles of 256 float4s

    if (bid >= NBLK) {
        // ---- pack-only block: static tile range, zero synchronization ----
        const int pk = bid - NBLK;
        const int PK = (int)gridDim.x - NBLK;
        const int t0 = (int)((long long)pk * T / PK);
        const int t1 = (int)((long long)(pk + 1) * T / PK);
        for (int t = t0; t < t1; ++t)
            pack_body(x, xh, n4, t * 256 + tid);
        return;
    }

    // ---- role block ----
    // P0: histogram of chunk bid
    {
        int* cnt = smem;
        for (int b = tid; b < NBIN; b += 256) cnt[b] = 0;
        __syncthreads();
        const int e0 = bid * CH;
        #pragma unroll
        for (int k = 0; k < CH / 1024; ++k) {
            const int g = (e0 >> 2) + k * 256 + tid;
            const int e = g << 2;
            if (e >= E) continue;
            if (e + 4 <= E) {
                const int4 d4 = reinterpret_cast<const int4*>(dst)[g];
                atomicAdd(&cnt[d4.x >> BSHIFT], 1);
                atomicAdd(&cnt[d4.y >> BSHIFT], 1);
                atomicAdd(&cnt[d4.z >> BSHIFT], 1);
                atomicAdd(&cnt[d4.w >> BSHIFT], 1);
            } else {
                for (int ee = e; ee < E; ++ee) atomicAdd(&cnt[dst[ee] >> BSHIFT], 1);
            }
        }
        __syncthreads();
        int* hb = hist_bm + (size_t)bid * NBIN;
        for (int b = tid; b < NBIN; b += 256) hb[b] = cnt[b];
    }
    __syncthreads();
    if (tid == 0)
        __hip_atomic_fetch_add(&bar[0], 1u, __ATOMIC_RELEASE, __HIP_MEMORY_SCOPE_AGENT);

    // P1: scan role (blocks 0..nb1-1)
    if (bid < nb1) {
        if (tid == 0) wait_count_relaxed(&bar[0], (unsigned)NBLK);
        __syncthreads();

        int (*tile)[NBLKCAP + 1] = reinterpret_cast<int(*)[NBLKCAP + 1]>(smem);
        int* sdt = smem + TBINS * (NBLKCAP + 1);
        const int B0 = bid * TBINS;
        for (int g = tid; g < TBINS * (NBLKCAP + 1); g += 256)
            (&tile[0][0])[g] = 0;
        __syncthreads();
        for (int g = tid; g < NBLK * TBINS; g += 256) {
            const int blk = g >> 4;
            const int tb  = g & (TBINS - 1);
            const int bin = B0 + tb;
            if (bin < NBIN) tile[tb][blk] = hist_bm[(size_t)blk * NBIN + bin];
        }
        __syncthreads();
        const int tb  = tid >> 4;
        const int bk0 = (tid & 15) * 16;
        int v[16];
        int local = 0;
        #pragma unroll
        for (int k = 0; k < 16; ++k) { v[k] = tile[tb][bk0 + k]; local += v[k]; }
        sdt[tid] = local;
        __syncthreads();
        #pragma unroll
        for (int off = 1; off < 256; off <<= 1) {
            int val = (tid >= off) ? sdt[tid - off] : 0;
            __syncthreads();
            sdt[tid] += val;
            __syncthreads();
        }
        const int incl = sdt[tid];
        int run = incl - local;
        if (tid == 255) blocksum[bid] = incl;   // raw total
        const int bin = B0 + tb;
        if (bin < NBIN) {
            #pragma unroll
            for (int k = 0; k < 16; ++k) {
                const int blk = bk0 + k;
                if (blk < NBLK) partial[(size_t)bin * NBLK + blk] = run;
                run += v[k];
            }
        }
        __syncthreads();
        if (tid == 0)
            __hip_atomic_fetch_add(&bar[32], 1u, __ATOMIC_RELEASE, __HIP_MEMORY_SCOPE_AGENT);
    }

    // P2: place role (all role blocks)
    if (tid == 0) wait_count_relaxed(&bar[32], (unsigned)nb1);
    __syncthreads();

    {   // in-LDS exclusive scan of raw blocksum totals
        int* lcur = smem;                        // 4096
        int* sd   = smem + MAXBIN;               // 256
        int* sb   = smem + MAXBIN + 256;         // 256
        sd[tid] = (tid < nb1) ? blocksum[tid] : 0;
        const int own = sd[tid];
        __syncthreads();
        #pragma unroll
        for (int off = 1; off < 256; off <<= 1) {
            int val = (tid >= off) ? sd[tid - off] : 0;
            __syncthreads();
            sd[tid] += val;
            __syncthreads();
        }
        sb[tid] = sd[tid] - own;
        __syncthreads();

        for (int b = tid; b < NBIN; b += 256)
            lcur[b] = partial[(size_t)b * NBLK + bid] + sb[b / TBINS];
        __syncthreads();

        const int e0 = bid * CH;
        #pragma unroll
        for (int k = 0; k < CH / 1024; ++k) {
            const int g = (e0 >> 2) + k * 256 + tid;
            const int e = g << 2;
            if (e >= E) continue;
            if (e + 4 <= E) {
                const int4 d4 = reinterpret_cast<const int4*>(dst)[g];
                const int4 s4 = reinterpret_cast<const int4*>(src)[g];
                int p;
                p = atomicAdd(&lcur[d4.x >> BSHIFT], 1);
                coarse[p] = (unsigned)s4.x | ((unsigned)(d4.x & (BWIDTH - 1)) << 17);
                p = atomicAdd(&lcur[d4.y >> BSHIFT], 1);
                coarse[p] = (unsigned)s4.y | ((unsigned)(d4.y & (BWIDTH - 1)) << 17);
                p = atomicAdd(&lcur[d4.z >> BSHIFT], 1);
                coarse[p] = (unsigned)s4.z | ((unsigned)(d4.z & (BWIDTH - 1)) << 17);
                p = atomicAdd(&lcur[d4.w >> BSHIFT], 1);
                coarse[p] = (unsigned)s4.w | ((unsigned)(d4.w & (BWIDTH - 1)) << 17);
            } else {
                for (int ee = e; ee < E; ++ee) {
                    const int d = dst[ee], s = src[ee];
                    int p = atomicAdd(&lcur[d >> BSHIFT], 1);
                    coarse[p] = (unsigned)s | ((unsigned)(d & (BWIDTH - 1)) << 17);
                }
            }
        }
    }
}

// ---------------- per-bin LDS counting sort + fused accumulation (R13) ----------------

__global__ __launch_bounds__(256) void k_sort_accum(
    const __half* __restrict__ xh,
    const float* __restrict__ W2,
    const float* __restrict__ W3,
    const unsigned int* __restrict__ coarse,
    const int* __restrict__ partial, const int* __restrict__ blocksum,
    int NBIN, int NBLK, int nb1, int E, int N,
    float* __restrict__ out)
{
    __shared__ unsigned int raw[LDSCAP];
    __shared__ int srcl[LDSCAP];
    __shared__ int cnt[BWIDTH], offs[BWIDTH], cur[BWIDTH];

    const int bin  = blockIdx.x;
    const int tid  = threadIdx.x;
    const int lane = tid & 63;
    const int grp  = lane >> 4;
    const int sl   = lane & 15;
    const int gid  = (tid >> 6) * 4 + grp;
    const int choff = sl << 4;
    const char* xb = (const char*)xh;

    union H { int4 i4; __half2 h[4]; };

    const int node0 = (bin << BSHIFT) + gid * 2;
    const int node1 = node0 + 1;
    H uD0, uD1;
    uD0.i4 = make_int4(0, 0, 0, 0);
    uD1.i4 = make_int4(0, 0, 0, 0);
    if (node0 < N) uD0.i4 = *reinterpret_cast<const int4*>(xb + (((size_t)node0) << 8) + choff);
    if (node1 < N) uD1.i4 = *reinterpret_cast<const int4*>(xb + (((size_t)node1) << 8) + choff);

    const int j1 = bin / TBINS;
    const int j2 = (bin + 1) / TBINS;
    int s = 0;
    #pragma unroll
    for (int k = 0; k < 4; ++k) {
        const int idx = lane + k * 64;
        if (idx < j1) s += blocksum[idx];
    }
    #pragma unroll
    for (int off = 32; off > 0; off >>= 1) s += __shfl_xor(s, off, 64);
    const int pref1 = s;
    const int pref2 = pref1 + ((j2 > j1 && j2 <= nb1) ? blocksum[j1] : 0);

    const size_t i0 = (size_t)bin * NBLK;
    const int beg = partial[i0] + pref1;
    const int end = (bin + 1 < NBIN) ? partial[i0 + NBLK] + pref2 : E;
    const int mtot = end - beg;
    const int m = (mtot < LDSCAP) ? mtot : LDSCAP;

    if (tid < BWIDTH) cnt[tid] = 0;
    __syncthreads();

    for (int i = tid; i < m; i += 256) {
        unsigned u = coarse[beg + i];
        raw[i] = u;
        atomicAdd(&cnt[u >> 17], 1);
    }
    __syncthreads();

    if (tid < BWIDTH) {
        int c = cnt[tid];
        int v = c;
        #pragma unroll
        for (int d2 = 1; d2 < BWIDTH; d2 <<= 1) {
            int t2 = __shfl_up(v, d2, 64);
            if (tid >= d2) v += t2;
        }
        offs[tid] = v - c;
        cur[tid]  = v - c;
    }
    __syncthreads();

    for (int i = tid; i < m; i += 256) {
        const unsigned u = raw[i];
        const int p = atomicAdd(&cur[u >> 17], 1);
        srcl[p] = (int)(u & 0x1FFFFu);
    }
    __syncthreads();

    const float4 w3a = *reinterpret_cast<const float4*>(W3 + sl * 8);
    const float4 w3b = *reinterpret_cast<const float4*>(W3 + sl * 8 + 4);
    const float4 w2a = *reinterpret_cast<const float4*>(W2 + sl * 8);
    const float4 w2b = *reinterpret_cast<const float4*>(W2 + sl * 8 + 4);

    #pragma unroll
    for (int i = 0; i < 2; ++i) {
        const int node = (i == 0) ? node0 : node1;
        if (node >= N) continue;
        const int dl = gid * 2 + i;
        const H uD = (i == 0) ? uD0 : uD1;

        const float2 e0 = __half22float2(uD.h[0]);
        const float2 e1 = __half22float2(uD.h[1]);
        const float2 e2 = __half22float2(uD.h[2]);
        const float2 e3 = __half22float2(uD.h[3]);
        half2_t vh[4];
        {
            __half2 t0 = __floats2half2_rn(w3a.x * e0.x, w3a.y * e0.y);
            __half2 t1 = __floats2half2_rn(w3a.z * e1.x, w3a.w * e1.y);
            __half2 t2 = __floats2half2_rn(w3b.x * e2.x, w3b.y * e2.y);
            __half2 t3 = __floats2half2_rn(w3b.z * e3.x, w3b.w * e3.y);
            vh[0] = *reinterpret_cast<half2_t*>(&t0);
            vh[1] = *reinterpret_cast<half2_t*>(&t1);
            vh[2] = *reinterpret_cast<half2_t*>(&t2);
            vh[3] = *reinterpret_cast<half2_t*>(&t3);
        }

        __half2 acc[4];
        acc[0] = __floats2half2_rn(0.f, 0.f);
        acc[1] = acc[0]; acc[2] = acc[0]; acc[3] = acc[0];

        const int b0 = offs[dl];
        const int c  = cnt[dl];

        int j = 0;
        for (; j + 4 <= c; j += 4) {
            const int s0 = srcl[b0 + j];
            const int s1 = srcl[b0 + j + 1];
            const int s2 = srcl[b0 + j + 2];
            const int s3 = srcl[b0 + j + 3];
            H u0, u1, u2, u3;
            u0.i4 = *reinterpret_cast<const int4*>(xb + (((size_t)s0) << 8) + choff);
            u1.i4 = *reinterpret_cast<const int4*>(xb + (((size_t)s1) << 8) + choff);
            u2.i4 = *reinterpret_cast<const int4*>(xb + (((size_t)s2) << 8) + choff);
            u3.i4 = *reinterpret_cast<const int4*>(xb + (((size_t)s3) << 8) + choff);
            float p0 = dot8_f16(u0.h, vh);
            float p1 = dot8_f16(u1.h, vh);
            float p2 = dot8_f16(u2.h, vh);
            float p3 = dot8_f16(u3.h, vh);
            #pragma unroll
            for (int off = 1; off < 16; off <<= 1) {
                p0 += __shfl_xor(p0, off, 64);
                p1 += __shfl_xor(p1, off, 64);
                p2 += __shfl_xor(p2, off, 64);
                p3 += __shfl_xor(p3, off, 64);
            }
            const __half2 ph0 = __half2half2(__float2half(p0));
            const __half2 ph1 = __half2half2(__float2half(p1));
            const __half2 ph2 = __half2half2(__float2half(p2));
            const __half2 ph3 = __half2half2(__float2half(p3));
            #pragma unroll
            for (int q = 0; q < 4; ++q) {
                acc[q] = __hfma2(ph0, u0.h[q], acc[q]);
                acc[q] = __hfma2(ph1, u1.h[q], acc[q]);
                acc[q] = __hfma2(ph2, u2.h[q], acc[q]);
                acc[q] = __hfma2(ph3, u3.h[q], acc[q]);
            }
        }
        for (; j < c; ++j) {
            H u0;
            u0.i4 = *reinterpret_cast<const int4*>(
                xb + (((size_t)srcl[b0 + j]) << 8) + choff);
            float p = dot8_f16(u0.h, vh);
            #pragma unroll
            for (int off = 1; off < 16; off <<= 1) p += __shfl_xor(p, off, 64);
            const __half2 ph = __half2half2(__float2half(p));
            #pragma unroll
            for (int q = 0; q < 4; ++q) acc[q] = __hfma2(ph, u0.h[q], acc[q]);
        }
        for (int i2 = LDSCAP; i2 < mtot; ++i2) {
            const unsigned u = coarse[beg + i2];
            if ((int)(u >> 17) != dl) continue;
            H u0;
            u0.i4 = *reinterpret_cast<const int4*>(
                xb + (((size_t)(u & 0x1FFFFu)) << 8) + choff);
            float p = dot8_f16(u0.h, vh);
            #pragma unroll
            for (int off = 1; off < 16; off <<= 1) p += __shfl_xor(p, off, 64);
            const __half2 ph = __half2half2(__float2half(p));
            #pragma unroll
            for (int q = 0; q < 4; ++q) acc[q] = __hfma2(ph, u0.h[q], acc[q]);
        }

        const float2 a0 = __half22float2(acc[0]);
        const float2 a1 = __half22float2(acc[1]);
        const float2 a2 = __half22float2(acc[2]);
        const float2 a3 = __half22float2(acc[3]);
        float4 oA = make_float4(a0.x * w2a.x, a0.y * w2a.y, a1.x * w2a.z, a1.y * w2a.w);
        float4 oB = make_float4(a2.x * w2b.x, a2.y * w2b.y, a3.x * w2b.z, a3.y * w2b.w);
        float* orow = out + (size_t)node * CCH + sl * 8;
        *reinterpret_cast<float4*>(orow)     = oA;
        *reinterpret_cast<float4*>(orow + 4) = oB;
    }
}

// ---------------- last-resort fallback: pure fp32 atomics (R1) ----------------

__global__ __launch_bounds__(256) void edge_gather_scatter(
    const float* __restrict__ x, const int* __restrict__ edge_index,
    const float* __restrict__ W2, const float* __restrict__ W3,
    float* __restrict__ out, int E)
{
    const int e    = (blockIdx.x * blockDim.x + threadIdx.x) >> 6;
    const int lane = threadIdx.x & 63;
    if (e >= E) return;
    const int s = edge_index[e];
    const int d = edge_index[E + e];
    const float2 xs = *reinterpret_cast<const float2*>(x + (size_t)s * CCH + lane * 2);
    const float2 xd = *reinterpret_cast<const float2*>(x + (size_t)d * CCH + lane * 2);
    const float2 w3 = *reinterpret_cast<const float2*>(W3 + lane * 2);
    const float2 w2 = *reinterpret_cast<const float2*>(W2 + lane * 2);
    float p = xs.x * w3.x * xd.x + xs.y * w3.y * xd.y;
    #pragma unroll
    for (int off = 32; off > 0; off >>= 1) p += __shfl_xor(p, off, 64);
    float* o = out + (size_t)d * CCH + lane * 2;
    atomicAdd(o,     p * xs.x * w2.x);
    atomicAdd(o + 1, p * xs.y * w2.y);
}

// ---------------- launch ----------------

extern "C" void kernel_launch(void* const* d_in, const int* in_sizes, int n_in,
                              void* d_out, int out_size, void* d_ws, size_t ws_size,
                              hipStream_t stream) {
    const float* x          = (const float*)d_in[0];
    const int*   edge_index = (const int*)  d_in[1];
    const float* W2         = (const float*)d_in[2];
    const float* W3         = (const float*)d_in[3];
    float*       out        = (float*)d_out;

    const int E = in_sizes[1] / 2;
    const int N = out_size / CCH;
    const int* src = edge_index;
    const int* dst = edge_index + E;

    const int NBIN = (N + BWIDTH - 1) >> BSHIFT;
    const int NBLK = (E + CH - 1) / CH;
    const long long Mll = (long long)NBIN * NBLK;
    const int M = (int)Mll;
    const int nb1 = (NBIN + TBINS - 1) / TBINS;

    const size_t xh_bytes = (size_t)N * CCH * 2;
    const size_t need = xh_bytes + (size_t)E * 4 + 2 * (size_t)M * 4 + 1024 * 4 + 256;

    const bool aligned16 = (((uintptr_t)src & 15) == 0) && (((uintptr_t)dst & 15) == 0);

    if (N <= (1 << 17) && NBIN <= MAXBIN && NBLK <= NBLKCAP && Mll <= (1LL << 20) &&
        nb1 <= 256 && NBLK + 64 <= NBA && aligned16 && ws_size >= need) {
        char* base = (char*)d_ws;
        __half* xh        = (__half*)base;       base += xh_bytes;
        unsigned* coarse  = (unsigned*)base;     base += (size_t)E * 4;
        int* hist_bm      = (int*)base;          base += (size_t)M * 4;
        int* partial      = (int*)base;          base += (size_t)M * 4;
        int* blocksum     = (int*)base;          base += 1024 * 4;
        unsigned* bar     = (unsigned*)base;     // bar[0] @ +0, bar[32] @ +128

        const int n4 = N * CCH / 4;

        hipMemsetAsync(bar, 0, 256, stream);
        k_preproc<<<NBA, 256, 0, stream>>>(x, xh, n4, src, dst, E,
                                           NBIN, NBLK, nb1,
                                           hist_bm, partial, blocksum, coarse,
                                           bar);
        k_sort_accum<<<NBIN, 256, 0, stream>>>(xh, W2, W3, coarse,
                                               partial, blocksum,
                                               NBIN, NBLK, nb1, E, N, out);
        return;
    }

    // last resort: pure atomics
    hipMemsetAsync(d_out, 0, (size_t)out_size * sizeof(float), stream);
    const int grid = (E * 64 + 255) / 256;
    edge_gather_scatter<<<grid, 256, 0, stream>>>(x, edge_index, W2, W3, out, E);
}

// Round 17
// 119.729 us; speedup vs baseline: 1.7088x; 1.2921x over previous
//
#include <hip/hip_runtime.h>
#include <hip/hip_fp16.h>

// out[n,c] = sum_{e: dst[e]==n} ( sum_k x[src[e],k]*W3[k]*x[dst[e],k] ) * x[src[e],c] * W2[c]
// B=1, N=100000, E=1600000, C=128.
//
// R17 = exact revert to R13 (best measured: 119.4us).
// Pipeline (4 launches; fp16 pack spread as a co-role across the first three):
//   k_hist_pack : hist-role blocks (coarse-bin histogram, bin=dst>>5) + pack
//   k_pscan_pack: scan-role blocks (LDS-tiled transpose scan; blocksum = raw
//                 per-scanblock totals) + pack
//   k_place_pack: place-role blocks (deterministic placement of (dstlow|src);
//                 blocksum prefix folded in via in-LDS scan) + pack
//   k_sort_accum: per-bin LDS counting sort + fused accumulation
//                 (fdot2 dot, hfma2 accum, dst prefetch, 4-deep ladder).
// Fallback: R1-style pure-atomic kernel if constraints unmet.

#define CCH 128
#define BSHIFT 5
#define BWIDTH 32              // nodes per bin
#define MAXBIN 4096            // supports N <= 131072 (17-bit src pack)
#define CH 8192                // edges per partition block
#define LDSCAP 1280            // max edges staged per bin (mean ~512)
#define TBINS 16               // bins per pscan block
#define NBLKCAP 256            // max partition blocks supported by pscan tile

typedef _Float16 half2_t __attribute__((ext_vector_type(2)));

__device__ __forceinline__ float dot8_f16(const __half2* q, const half2_t* v) {
#if __has_builtin(__builtin_amdgcn_fdot2)
    const half2_t* qv = reinterpret_cast<const half2_t*>(q);
    float p = __builtin_amdgcn_fdot2(qv[0], v[0], 0.f, false);
    p = __builtin_amdgcn_fdot2(qv[1], v[1], p, false);
    p = __builtin_amdgcn_fdot2(qv[2], v[2], p, false);
    p = __builtin_amdgcn_fdot2(qv[3], v[3], p, false);
    return p;
#else
    const __half2* vv = reinterpret_cast<const __half2*>(v);
    __half2 t = __hmul2(q[0], vv[0]);
    t = __hfma2(q[1], vv[1], t);
    t = __hfma2(q[2], vv[2], t);
    t = __hfma2(q[3], vv[3], t);
    float2 tf = __half22float2(t);
    return tf.x + tf.y;
#endif
}

// ---------------- pack helper (device inline) ----------------

__device__ __forceinline__ void pack_body(const float* __restrict__ x,
                                          __half* __restrict__ xh,
                                          int n4, int i) {
    if (i < n4) {
        float4 v = reinterpret_cast<const float4*>(x)[i];
        __half2* o = reinterpret_cast<__half2*>(xh) + (size_t)i * 2;
        o[0] = __floats2half2_rn(v.x, v.y);
        o[1] = __floats2half2_rn(v.z, v.w);
    }
}

// ---------------- L1: hist role + pack role ----------------

__global__ __launch_bounds__(256) void k_hist_pack(
    const int* __restrict__ dst, int E, int NBIN, int NBLK,
    int* __restrict__ hist_bm,
    const float* __restrict__ x, __half* __restrict__ xh, int n4, int pOff)
{
    __shared__ int cnt[MAXBIN];
    const int tid = threadIdx.x;

    if ((int)blockIdx.x >= NBLK) {            // pack role
        pack_body(x, xh, n4, (pOff + (int)blockIdx.x - NBLK) * 256 + tid);
        return;
    }

    const int blk = blockIdx.x;               // hist role
    for (int b = tid; b < NBIN; b += 256) cnt[b] = 0;
    __syncthreads();

    const int e0 = blk * CH;
    #pragma unroll
    for (int k = 0; k < CH / 1024; ++k) {
        const int g = (e0 >> 2) + k * 256 + tid;   // int4 index
        const int e = g << 2;
        if (e >= E) continue;
        if (e + 4 <= E) {
            const int4 d4 = reinterpret_cast<const int4*>(dst)[g];
            atomicAdd(&cnt[d4.x >> BSHIFT], 1);
            atomicAdd(&cnt[d4.y >> BSHIFT], 1);
            atomicAdd(&cnt[d4.z >> BSHIFT], 1);
            atomicAdd(&cnt[d4.w >> BSHIFT], 1);
        } else {
            for (int ee = e; ee < E; ++ee) atomicAdd(&cnt[dst[ee] >> BSHIFT], 1);
        }
    }
    __syncthreads();
    int* hb = hist_bm + (size_t)blk * NBIN;   // block-major, coalesced writes
    for (int b = tid; b < NBIN; b += 256) hb[b] = cnt[b];
}

// ---------------- L2: scan role + pack role ----------------

__global__ __launch_bounds__(256) void k_pscan_pack(
    const int* __restrict__ hist_bm, int NBIN, int NBLK, int nb1,
    int* __restrict__ partial, int* __restrict__ blocksum,
    const float* __restrict__ x, __half* __restrict__ xh, int n4, int pOff)
{
    __shared__ int tile[TBINS][NBLKCAP + 1];
    __shared__ int sdata[256];
    const int t = threadIdx.x;

    if ((int)blockIdx.x >= nb1) {             // pack role
        pack_body(x, xh, n4, (pOff + (int)blockIdx.x - nb1) * 256 + t);
        return;
    }

    const int B0 = blockIdx.x * TBINS;        // scan role

    for (int g = t; g < TBINS * (NBLKCAP + 1); g += 256)
        (&tile[0][0])[g] = 0;
    __syncthreads();

    for (int g = t; g < NBLK * TBINS; g += 256) {
        const int blk = g >> 4;               // g / TBINS
        const int tb  = g & (TBINS - 1);
        const int bin = B0 + tb;
        if (bin < NBIN) tile[tb][blk] = hist_bm[(size_t)blk * NBIN + bin];
    }
    __syncthreads();

    const int tb  = t >> 4;
    const int bk0 = (t & 15) * 16;
    int v[16];
    int local = 0;
    #pragma unroll
    for (int k = 0; k < 16; ++k) { v[k] = tile[tb][bk0 + k]; local += v[k]; }

    sdata[t] = local;
    __syncthreads();
    #pragma unroll
    for (int off = 1; off < 256; off <<= 1) {
        int val = (t >= off) ? sdata[t - off] : 0;
        __syncthreads();
        sdata[t] += val;
        __syncthreads();
    }
    const int incl = sdata[t];
    int run = incl - local;
    if (t == 255) blocksum[blockIdx.x] = incl;   // raw total

    const int bin = B0 + tb;
    if (bin < NBIN) {
        #pragma unroll
        for (int k = 0; k < 16; ++k) {
            const int blk = bk0 + k;
            if (blk < NBLK) partial[(size_t)bin * NBLK + blk] = run;
            run += v[k];
        }
    }
}

// ---------------- L3: place role (+ in-LDS blocksum scan) + pack role ----------------

__global__ __launch_bounds__(256) void k_place_pack(
    const int* __restrict__ src, const int* __restrict__ dst, int E,
    int NBIN, int NBLK, int nb1,
    const int* __restrict__ partial, const int* __restrict__ blocksum,
    unsigned int* __restrict__ coarse,
    const float* __restrict__ x, __half* __restrict__ xh, int n4, int pOff)
{
    __shared__ int lcur[MAXBIN];
    __shared__ int sdata[256];
    __shared__ int sblk[256];
    const int tid = threadIdx.x;

    if ((int)blockIdx.x >= NBLK) {            // pack role
        pack_body(x, xh, n4, (pOff + (int)blockIdx.x - NBLK) * 256 + tid);
        return;
    }

    // exclusive scan of the (<=256) raw blocksum totals, once per block
    sdata[tid] = (tid < nb1) ? blocksum[tid] : 0;
    const int own = sdata[tid];
    __syncthreads();
    #pragma unroll
    for (int off = 1; off < 256; off <<= 1) {
        int val = (tid >= off) ? sdata[tid - off] : 0;
        __syncthreads();
        sdata[tid] += val;
        __syncthreads();
    }
    sblk[tid] = sdata[tid] - own;             // exclusive prefix
    __syncthreads();

    const int blk = blockIdx.x;               // place role
    for (int b = tid; b < NBIN; b += 256) {
        lcur[b] = partial[(size_t)b * NBLK + blk] + sblk[b / TBINS];
    }
    __syncthreads();

    const int e0 = blk * CH;
    #pragma unroll
    for (int k = 0; k < CH / 1024; ++k) {
        const int g = (e0 >> 2) + k * 256 + tid;
        const int e = g << 2;
        if (e >= E) continue;
        if (e + 4 <= E) {
            const int4 d4 = reinterpret_cast<const int4*>(dst)[g];
            const int4 s4 = reinterpret_cast<const int4*>(src)[g];
            int p;
            p = atomicAdd(&lcur[d4.x >> BSHIFT], 1);
            coarse[p] = (unsigned)s4.x | ((unsigned)(d4.x & (BWIDTH - 1)) << 17);
            p = atomicAdd(&lcur[d4.y >> BSHIFT], 1);
            coarse[p] = (unsigned)s4.y | ((unsigned)(d4.y & (BWIDTH - 1)) << 17);
            p = atomicAdd(&lcur[d4.z >> BSHIFT], 1);
            coarse[p] = (unsigned)s4.z | ((unsigned)(d4.z & (BWIDTH - 1)) << 17);
            p = atomicAdd(&lcur[d4.w >> BSHIFT], 1);
            coarse[p] = (unsigned)s4.w | ((unsigned)(d4.w & (BWIDTH - 1)) << 17);
        } else {
            for (int ee = e; ee < E; ++ee) {
                const int d = dst[ee], s = src[ee];
                int p = atomicAdd(&lcur[d >> BSHIFT], 1);
                coarse[p] = (unsigned)s | ((unsigned)(d & (BWIDTH - 1)) << 17);
            }
        }
    }
}

// ---------------- L4: per-bin LDS counting sort + fused accumulation ----------------
// 16 groups of 16 lanes; group gid owns nodes gid*2, gid*2+1. Lane sl owns
// channels sl*8..sl*8+7 (16B fp16 loads). 4-deep gather ladder; dst rows
// prefetched before the sort barriers; fdot2 dot + fp16 hfma2 accumulation.

__global__ __launch_bounds__(256) void k_sort_accum(
    const __half* __restrict__ xh,
    const float* __restrict__ W2,
    const float* __restrict__ W3,
    const unsigned int* __restrict__ coarse,
    const int* __restrict__ partial, const int* __restrict__ blocksum,
    int NBIN, int NBLK, int nb1, int E, int N,
    float* __restrict__ out)
{
    __shared__ unsigned int raw[LDSCAP];
    __shared__ int srcl[LDSCAP];
    __shared__ int cnt[BWIDTH], offs[BWIDTH], cur[BWIDTH];

    const int bin  = blockIdx.x;
    const int tid  = threadIdx.x;
    const int lane = tid & 63;
    const int grp  = lane >> 4;
    const int sl   = lane & 15;
    const int gid  = (tid >> 6) * 4 + grp;
    const int choff = sl << 4;
    const char* xb = (const char*)xh;

    union H { int4 i4; __half2 h[4]; };

    // prefetch this group's two dst rows (latency hidden under the sort)
    const int node0 = (bin << BSHIFT) + gid * 2;
    const int node1 = node0 + 1;
    H uD0, uD1;
    uD0.i4 = make_int4(0, 0, 0, 0);
    uD1.i4 = make_int4(0, 0, 0, 0);
    if (node0 < N) uD0.i4 = *reinterpret_cast<const int4*>(xb + (((size_t)node0) << 8) + choff);
    if (node1 < N) uD1.i4 = *reinterpret_cast<const int4*>(xb + (((size_t)node1) << 8) + choff);

    // per-wave prefix of raw blocksum totals
    const int j1 = bin / TBINS;
    const int j2 = (bin + 1) / TBINS;
    int s = 0;
    #pragma unroll
    for (int k = 0; k < 4; ++k) {
        const int idx = lane + k * 64;
        if (idx < j1) s += blocksum[idx];
    }
    #pragma unroll
    for (int off = 32; off > 0; off >>= 1) s += __shfl_xor(s, off, 64);
    const int pref1 = s;
    const int pref2 = pref1 + ((j2 > j1 && j2 <= nb1) ? blocksum[j1] : 0);

    const size_t i0 = (size_t)bin * NBLK;
    const int beg = partial[i0] + pref1;
    const int end = (bin + 1 < NBIN) ? partial[i0 + NBLK] + pref2 : E;
    const int mtot = end - beg;
    const int m = (mtot < LDSCAP) ? mtot : LDSCAP;

    if (tid < BWIDTH) cnt[tid] = 0;
    __syncthreads();

    for (int i = tid; i < m; i += 256) {
        unsigned u = coarse[beg + i];
        raw[i] = u;
        atomicAdd(&cnt[u >> 17], 1);
    }
    __syncthreads();

    if (tid < BWIDTH) {                       // lanes 0..31 of wave 0
        int c = cnt[tid];
        int v = c;
        #pragma unroll
        for (int d2 = 1; d2 < BWIDTH; d2 <<= 1) {
            int t2 = __shfl_up(v, d2, 64);
            if (tid >= d2) v += t2;
        }
        offs[tid] = v - c;
        cur[tid]  = v - c;
    }
    __syncthreads();

    for (int i = tid; i < m; i += 256) {
        const unsigned u = raw[i];
        const int p = atomicAdd(&cur[u >> 17], 1);
        srcl[p] = (int)(u & 0x1FFFFu);
    }
    __syncthreads();

    const float4 w3a = *reinterpret_cast<const float4*>(W3 + sl * 8);
    const float4 w3b = *reinterpret_cast<const float4*>(W3 + sl * 8 + 4);
    const float4 w2a = *reinterpret_cast<const float4*>(W2 + sl * 8);
    const float4 w2b = *reinterpret_cast<const float4*>(W2 + sl * 8 + 4);

    #pragma unroll
    for (int i = 0; i < 2; ++i) {
        const int node = (i == 0) ? node0 : node1;
        if (node >= N) continue;
        const int dl = gid * 2 + i;
        const H uD = (i == 0) ? uD0 : uD1;

        // v = W3 .* x[node] for this lane's 8 channels, as 4 half2
        const float2 e0 = __half22float2(uD.h[0]);
        const float2 e1 = __half22float2(uD.h[1]);
        const float2 e2 = __half22float2(uD.h[2]);
        const float2 e3 = __half22float2(uD.h[3]);
        half2_t vh[4];
        {
            __half2 t0 = __floats2half2_rn(w3a.x * e0.x, w3a.y * e0.y);
            __half2 t1 = __floats2half2_rn(w3a.z * e1.x, w3a.w * e1.y);
            __half2 t2 = __floats2half2_rn(w3b.x * e2.x, w3b.y * e2.y);
            __half2 t3 = __floats2half2_rn(w3b.z * e3.x, w3b.w * e3.y);
            vh[0] = *reinterpret_cast<half2_t*>(&t0);
            vh[1] = *reinterpret_cast<half2_t*>(&t1);
            vh[2] = *reinterpret_cast<half2_t*>(&t2);
            vh[3] = *reinterpret_cast<half2_t*>(&t3);
        }

        __half2 acc[4];
        acc[0] = __floats2half2_rn(0.f, 0.f);
        acc[1] = acc[0]; acc[2] = acc[0]; acc[3] = acc[0];

        const int b0 = offs[dl];
        const int c  = cnt[dl];

        int j = 0;
        for (; j + 4 <= c; j += 4) {          // 4 gathers in flight per group
            const int s0 = srcl[b0 + j];
            const int s1 = srcl[b0 + j + 1];
            const int s2 = srcl[b0 + j + 2];
            const int s3 = srcl[b0 + j + 3];
            H u0, u1, u2, u3;
            u0.i4 = *reinterpret_cast<const int4*>(xb + (((size_t)s0) << 8) + choff);
            u1.i4 = *reinterpret_cast<const int4*>(xb + (((size_t)s1) << 8) + choff);
            u2.i4 = *reinterpret_cast<const int4*>(xb + (((size_t)s2) << 8) + choff);
            u3.i4 = *reinterpret_cast<const int4*>(xb + (((size_t)s3) << 8) + choff);
            float p0 = dot8_f16(u0.h, vh);
            float p1 = dot8_f16(u1.h, vh);
            float p2 = dot8_f16(u2.h, vh);
            float p3 = dot8_f16(u3.h, vh);
            #pragma unroll
            for (int off = 1; off < 16; off <<= 1) {
                p0 += __shfl_xor(p0, off, 64);
                p1 += __shfl_xor(p1, off, 64);
                p2 += __shfl_xor(p2, off, 64);
                p3 += __shfl_xor(p3, off, 64);
            }
            const __half2 ph0 = __half2half2(__float2half(p0));
            const __half2 ph1 = __half2half2(__float2half(p1));
            const __half2 ph2 = __half2half2(__float2half(p2));
            const __half2 ph3 = __half2half2(__float2half(p3));
            #pragma unroll
            for (int q = 0; q < 4; ++q) {
                acc[q] = __hfma2(ph0, u0.h[q], acc[q]);
                acc[q] = __hfma2(ph1, u1.h[q], acc[q]);
                acc[q] = __hfma2(ph2, u2.h[q], acc[q]);
                acc[q] = __hfma2(ph3, u3.h[q], acc[q]);
            }
        }
        for (; j < c; ++j) {
            H u0;
            u0.i4 = *reinterpret_cast<const int4*>(
                xb + (((size_t)srcl[b0 + j]) << 8) + choff);
            float p = dot8_f16(u0.h, vh);
            #pragma unroll
            for (int off = 1; off < 16; off <<= 1) p += __shfl_xor(p, off, 64);
            const __half2 ph = __half2half2(__float2half(p));
            #pragma unroll
            for (int q = 0; q < 4; ++q) acc[q] = __hfma2(ph, u0.h[q], acc[q]);
        }
        for (int i2 = LDSCAP; i2 < mtot; ++i2) {
            const unsigned u = coarse[beg + i2];
            if ((int)(u >> 17) != dl) continue;
            H u0;
            u0.i4 = *reinterpret_cast<const int4*>(
                xb + (((size_t)(u & 0x1FFFFu)) << 8) + choff);
            float p = dot8_f16(u0.h, vh);
            #pragma unroll
            for (int off = 1; off < 16; off <<= 1) p += __shfl_xor(p, off, 64);
            const __half2 ph = __half2half2(__float2half(p));
            #pragma unroll
            for (int q = 0; q < 4; ++q) acc[q] = __hfma2(ph, u0.h[q], acc[q]);
        }

        const float2 a0 = __half22float2(acc[0]);
        const float2 a1 = __half22float2(acc[1]);
        const float2 a2 = __half22float2(acc[2]);
        const float2 a3 = __half22float2(acc[3]);
        float4 oA = make_float4(a0.x * w2a.x, a0.y * w2a.y, a1.x * w2a.z, a1.y * w2a.w);
        float4 oB = make_float4(a2.x * w2b.x, a2.y * w2b.y, a3.x * w2b.z, a3.y * w2b.w);
        float* orow = out + (size_t)node * CCH + sl * 8;
        *reinterpret_cast<float4*>(orow)     = oA;
        *reinterpret_cast<float4*>(orow + 4) = oB;
    }
}

// ---------------- last-resort fallback: pure fp32 atomics (R1) ----------------

__global__ __launch_bounds__(256) void edge_gather_scatter(
    const float* __restrict__ x, const int* __restrict__ edge_index,
    const float* __restrict__ W2, const float* __restrict__ W3,
    float* __restrict__ out, int E)
{
    const int e    = (blockIdx.x * blockDim.x + threadIdx.x) >> 6;
    const int lane = threadIdx.x & 63;
    if (e >= E) return;
    const int s = edge_index[e];
    const int d = edge_index[E + e];
    const float2 xs = *reinterpret_cast<const float2*>(x + (size_t)s * CCH + lane * 2);
    const float2 xd = *reinterpret_cast<const float2*>(x + (size_t)d * CCH + lane * 2);
    const float2 w3 = *reinterpret_cast<const float2*>(W3 + lane * 2);
    const float2 w2 = *reinterpret_cast<const float2*>(W2 + lane * 2);
    float p = xs.x * w3.x * xd.x + xs.y * w3.y * xd.y;
    #pragma unroll
    for (int off = 32; off > 0; off >>= 1) p += __shfl_xor(p, off, 64);
    float* o = out + (size_t)d * CCH + lane * 2;
    atomicAdd(o,     p * xs.x * w2.x);
    atomicAdd(o + 1, p * xs.y * w2.y);
}

// ---------------- launch ----------------

extern "C" void kernel_launch(void* const* d_in, const int* in_sizes, int n_in,
                              void* d_out, int out_size, void* d_ws, size_t ws_size,
                              hipStream_t stream) {
    const float* x          = (const float*)d_in[0];
    const int*   edge_index = (const int*)  d_in[1];
    const float* W2         = (const float*)d_in[2];
    const float* W3         = (const float*)d_in[3];
    float*       out        = (float*)d_out;

    const int E = in_sizes[1] / 2;
    const int N = out_size / CCH;
    const int* src = edge_index;
    const int* dst = edge_index + E;

    const int NBIN = (N + BWIDTH - 1) >> BSHIFT;
    const int NBLK = (E + CH - 1) / CH;
    const long long Mll = (long long)NBIN * NBLK;
    const int M = (int)Mll;
    const int nb1 = (NBIN + TBINS - 1) / TBINS;

    const size_t xh_bytes = (size_t)N * CCH * 2;
    const size_t need = xh_bytes + (size_t)E * 4 + 2 * (size_t)M * 4 + 1024 * 4;

    const bool aligned16 = (((uintptr_t)src & 15) == 0) && (((uintptr_t)dst & 15) == 0);

    if (N <= (1 << 17) && NBIN <= MAXBIN && NBLK <= NBLKCAP && Mll <= (1LL << 20) &&
        nb1 <= 256 && aligned16 && ws_size >= need) {
        char* base = (char*)d_ws;
        __half* xh       = (__half*)base;        base += xh_bytes;
        unsigned* coarse = (unsigned*)base;      base += (size_t)E * 4;
        int* hist_bm     = (int*)base;           base += (size_t)M * 4;
        int* partial     = (int*)base;           base += (size_t)M * 4;
        int* blocksum    = (int*)base;

        const int n4 = N * CCH / 4;
        const int nPack = (n4 + 255) / 256;
        const int nP1 = (nPack * 35) / 100;
        const int nP2 = (nPack * 40) / 100;
        const int nP3 = nPack - nP1 - nP2;

        k_hist_pack<<<NBLK + nP1, 256, 0, stream>>>(dst, E, NBIN, NBLK, hist_bm,
                                                    x, xh, n4, 0);
        k_pscan_pack<<<nb1 + nP2, 256, 0, stream>>>(hist_bm, NBIN, NBLK, nb1,
                                                    partial, blocksum,
                                                    x, xh, n4, nP1);
        k_place_pack<<<NBLK + nP3, 256, 0, stream>>>(src, dst, E, NBIN, NBLK, nb1,
                                                     partial, blocksum, coarse,
                                                     x, xh, n4, nP1 + nP2);
        k_sort_accum<<<NBIN, 256, 0, stream>>>(xh, W2, W3, coarse,
                                               partial, blocksum,
                                               NBIN, NBLK, nb1, E, N, out);
        return;
    }

    // last resort: pure atomics
    hipMemsetAsync(d_out, 0, (size_t)out_size * sizeof(float), stream);
    const int grid = (E * 64 + 255) / 256;
    edge_gather_scatter<<<grid, 256, 0, stream>>>(x, edge_index, W2, W3, out, E);
}